// Round 10
// baseline (214.603 us; speedup 1.0000x reference)
//
#include <hip/hip_runtime.h>
#include <hip/hip_bf16.h>

typedef __bf16 bf16;
typedef __attribute__((ext_vector_type(4))) __bf16 bf16x4;
typedef __attribute__((ext_vector_type(8))) __bf16 bf16x8;
typedef __attribute__((ext_vector_type(4))) float f32x4;
typedef __attribute__((ext_vector_type(4))) short short4v;

#define AS1C(p) ((const __attribute__((address_space(1))) void*)(p))
#define AS3(p)  ((__attribute__((address_space(3))) void*)(p))

static constexpr int B_ = 2, S_ = 2048, DM = 1024, H_ = 16, DK = 64;
static constexpr int M_ = B_ * S_;   // 4096 tokens
static constexpr int NW = DM * DM;   // 1M weight elems
static constexpr float QSCL = 0.125f * 1.44269504088896340736f;  // (1/sqrt dk)*log2(e)

__device__ __forceinline__ float fast_exp2(float x) {
#if __has_builtin(__builtin_amdgcn_exp2f)
  return __builtin_amdgcn_exp2f(x);
#else
  return exp2f(x);
#endif
}

// 16x16x16 bf16 MFMA (K=16): lets the S^T C-layout (col=l16,row=quad*4+r)
// feed PV's B-operand (col=l16,k=quad*4+j) directly from registers.
__device__ __forceinline__ f32x4 mfma_pv(bf16x4 a, bf16x4 b, f32x4 c) {
#if __has_builtin(__builtin_amdgcn_mfma_f32_16x16x16_bf16)
  return __builtin_amdgcn_mfma_f32_16x16x16_bf16(a, b, c, 0, 0, 0);
#else
  union U { bf16x4 h; short4v s; };
  U ua; ua.h = a;
  U ub; ub.h = b;
  return __builtin_amdgcn_mfma_f32_16x16x16bf16_1k(ua.s, ub.s, c, 0, 0, 0);
#endif
}

// V tok-permutation within each 32-tok group: lets attn read ONE b128 =
// A-frags for TWO adjacent ct tiles (lo/hi bf16x4). Applied at Vtg write.
__device__ __forceinline__ int vperm_tok(int tok) {
  const int t5 = tok & 31;
  return (tok & ~31) | (((t5 >> 2) & 3) * 8) | (((t5 >> 4) & 1) * 4);
  // (t5&3 == 0 at all call sites; the bf16x4 vector write covers r=0..3)
}

// ---------------------------------------------------------------------------
// cast_all: fp32 -> bf16 for weights AND (optionally) activations.
//   id <  512: Wq * QSCL -> Wc[0] | id <1024: Wk | id <1536: Wv | id <2048: Wo
//   id < 4096: q -> qc | id < 6144: k -> kc | id < 8192: v -> vc
// ---------------------------------------------------------------------------
__global__ __launch_bounds__(256) void cast_all(
    const float* Wq, const float* Wk, const float* Wv, const float* Wo,
    const float* q, const float* k, const float* v,
    bf16* Wc, bf16* WoC, bf16* qc, bf16* kc, bf16* vc)
{
  const int id = blockIdx.x;
  const float* in;
  bf16* out;
  float s = 1.0f;
  int base;
  if (id < 2048) {
    const int z = id >> 9;           // 512 blocks per weight
    base = id & 511;
    in  = z == 0 ? Wq : (z == 1 ? Wk : (z == 2 ? Wv : Wo));
    out = z < 3 ? (Wc + (size_t)z * NW) : WoC;
    if (z == 0) s = QSCL;
  } else {
    const int z = (id - 2048) >> 11; // 2048 blocks per activation
    base = (id - 2048) & 2047;
    in  = z == 0 ? q : (z == 1 ? k : v);
    out = z == 0 ? qc : (z == 1 ? kc : vc);
  }
  const size_t i = ((size_t)base * 256 + threadIdx.x) * 8;
  f32x4 a = *(const f32x4*)(in + i);
  f32x4 b2 = *(const f32x4*)(in + i + 4);
  bf16x8 o;
#pragma unroll
  for (int j = 0; j < 4; ++j) { o[j] = (bf16)(a[j] * s); o[4 + j] = (bf16)(b2[j] * s); }
  *(bf16x8*)(out + i) = o;
}

// ---------------------------------------------------------------------------
// gemm_qkv_b (preferred, needs 56MB ws): pure-bf16 m97-structure GEMM.
// Per K-step: barrier / glds A + glds W / barrier(drain) / 32 MFMA.
// Flat grid 768 (3/CU), XCD swizzle. transv (z==2) writes Vtg with the
// vperm tok order (see vperm_tok).
// ---------------------------------------------------------------------------
__global__ __launch_bounds__(256, 3) void gemm_qkv_b(
    const bf16* __restrict__ qc, const bf16* __restrict__ kc,
    const bf16* __restrict__ vc, const bf16* __restrict__ Wc,
    const float* b0, const float* b1, const float* b2,
    bf16* C0, bf16* C1, bf16* C2, int M, int N, int K)
{
  const int id = blockIdx.x;
  const int z  = id >> 8;            // 0..2
  const int r  = id & 255;
  const int by = r & 31;             // same-by blocks: ids differ by 32
  const int bx = r >> 5;             // 0..7
  const bf16* A = z == 0 ? qc : (z == 1 ? kc : vc);
  const float* bias = z == 0 ? b0 : (z == 1 ? b1 : b2);
  const float bscale = z == 0 ? QSCL : 1.0f;
  const bf16* W = Wc + (size_t)z * NW;
  bf16* Cout = z == 0 ? C0 : (z == 1 ? C1 : C2);
  const bool transv = (z == 2);

  __shared__ bf16 As[2 * 128 * 32];   // [hf][row][32], 16 KB
  __shared__ bf16 Bs[2 * 128 * 32];

  const int tid  = threadIdx.x;
  const int wave = tid >> 6, lane = tid & 63;
  const int quad = lane >> 4, l16 = lane & 15;
  const int wm = wave >> 1, wn = wave & 1;
  const int row0 = by * 128;
  const int col0 = bx * 128;

  const int srow  = lane >> 2;        // glds lane mapping
  const int skcol = (lane & 3) * 8;

  f32x4 acc[4][4] = {};

  for (int k0 = 0; k0 < K; k0 += 64) {
    __syncthreads();                  // prev iter's LDS reads done
#pragma unroll
    for (int hf = 0; hf < 2; ++hf)
#pragma unroll
      for (int c = wave; c < 8; c += 4)
        __builtin_amdgcn_global_load_lds(
            AS1C(A + (size_t)(row0 + c * 16 + srow) * K + k0 + hf * 32 + skcol),
            AS3(As + hf * 4096 + c * 512), 16, 0, 0);
#pragma unroll
    for (int hf = 0; hf < 2; ++hf)
#pragma unroll
      for (int i = 0; i < 2; ++i) {
        const int c = wave * 2 + i;
        __builtin_amdgcn_global_load_lds(
            AS1C(W + (size_t)(col0 + c * 16 + srow) * K + k0 + hf * 32 + skcol),
            AS3(Bs + hf * 4096 + c * 512), 16, 0, 0);
      }
    __syncthreads();                  // staging ready (drains vmcnt)

#pragma unroll
    for (int hf = 0; hf < 2; ++hf) {
      bf16x8 a[4], bfr[4];
#pragma unroll
      for (int i = 0; i < 4; ++i)
        a[i] = *(const bf16x8*)(As + hf * 4096 + (wm * 64 + i * 16 + l16) * 32 + quad * 8);
#pragma unroll
      for (int j = 0; j < 4; ++j)
        bfr[j] = *(const bf16x8*)(Bs + hf * 4096 + (wn * 64 + j * 16 + l16) * 32 + quad * 8);
#pragma unroll
      for (int i = 0; i < 4; ++i)
#pragma unroll
        for (int j = 0; j < 4; ++j)
          acc[i][j] = __builtin_amdgcn_mfma_f32_16x16x32_bf16(a[i], bfr[j], acc[i][j], 0, 0, 0);
    }
  }

  // Epilogue: C/D layout col = lane&15, row = quad*4 + reg
#pragma unroll
  for (int j = 0; j < 4; ++j) {
    const int col = col0 + wn * 64 + j * 16 + l16;
    const float bv = bias[col] * bscale;
    if (transv) {
      const int hh = col >> 6, dd = col & 63;
#pragma unroll
      for (int i = 0; i < 4; ++i) {
        const int row = row0 + wm * 64 + i * 16 + quad * 4;
        const int bb2 = row >> 11, tok = row & 2047;
        const int tokp = vperm_tok(tok);
        bf16x4 o;
#pragma unroll
        for (int r2 = 0; r2 < 4; ++r2) o[r2] = (bf16)(acc[i][j][r2] + bv);
        *(bf16x4*)(Cout + (((size_t)bb2 * H_ + hh) * DK + dd) * S_ + tokp) = o;
      }
    } else {
#pragma unroll
      for (int i = 0; i < 4; ++i)
#pragma unroll
        for (int r2 = 0; r2 < 4; ++r2) {
          const int row = row0 + wm * 64 + i * 16 + quad * 4 + r2;
          Cout[(size_t)row * N + col] = (bf16)(acc[i][j][r2] + bv);
        }
    }
  }
}

// ---------------------------------------------------------------------------
// gemm_qkv_f (fallback, 32MB ws): fp32-A path, exact R2/R4 schedule.
// transv epilogue uses the same vperm tok order.
// ---------------------------------------------------------------------------
__global__ __launch_bounds__(256) void gemm_qkv_f(
    const float* A0, const float* A1, const float* A2,
    const bf16* __restrict__ Wc,
    const float* b0, const float* b1, const float* b2,
    bf16* C0, bf16* C1, bf16* C2, int M, int N, int K)
{
  const int id = blockIdx.x;
  const int z  = id >> 8;            // 0..2
  const int r  = id & 255;
  const int by = r & 31;             // same-by blocks: ids differ by 32
  const int bx = r >> 5;             // 0..7
  const float* A = z == 0 ? A0 : (z == 1 ? A1 : A2);
  const float* bias = z == 0 ? b0 : (z == 1 ? b1 : b2);
  const float bscale = z == 0 ? QSCL : 1.0f;
  const bf16* W = Wc + (size_t)z * NW;
  bf16* Cout = z == 0 ? C0 : (z == 1 ? C1 : C2);
  const bool transv = (z == 2);

  __shared__ bf16 As[2 * 128 * 32];   // [hf][row][32]
  __shared__ bf16 Bs[2 * 128 * 32];

  const int tid  = threadIdx.x;
  const int wave = tid >> 6, lane = tid & 63;
  const int quad = lane >> 4, l16 = lane & 15;
  const int wm = wave >> 1, wn = wave & 1;
  const int row0 = by * 128;
  const int col0 = bx * 128;

  const int srow  = lane >> 2;        // glds lane mapping
  const int skcol = (lane & 3) * 8;

  const int arow  = (tid >> 1) & 127;
  const int ak16  = (tid & 1) * 16;
  const float* agp = A + (size_t)(row0 + arow) * K + ak16;
  f32x4 pre[8];
#pragma unroll
  for (int hf = 0; hf < 2; ++hf)
#pragma unroll
    for (int c = 0; c < 4; ++c)
      pre[hf * 4 + c] = *(const f32x4*)(agp + hf * 32 + c * 4);

  f32x4 acc[4][4] = {};

  for (int k0 = 0; k0 < K; k0 += 64) {
    __syncthreads();                  // prev iter's LDS reads done
#pragma unroll
    for (int hf = 0; hf < 2; ++hf) {
      bf16x8 w0, w1;
#pragma unroll
      for (int j = 0; j < 4; ++j) {
        w0[j]     = (bf16)pre[hf * 4 + 0][j];
        w0[4 + j] = (bf16)pre[hf * 4 + 1][j];
        w1[j]     = (bf16)pre[hf * 4 + 2][j];
        w1[4 + j] = (bf16)pre[hf * 4 + 3][j];
      }
      bf16* dst = As + hf * 4096 + arow * 32 + ak16;
      *(bf16x8*)dst = w0;
      *(bf16x8*)(dst + 8) = w1;
    }
#pragma unroll
    for (int hf = 0; hf < 2; ++hf)
#pragma unroll
      for (int i = 0; i < 2; ++i) {
        const int c = wave * 2 + i;
        __builtin_amdgcn_global_load_lds(
            AS1C(W + (size_t)(col0 + c * 16 + srow) * K + k0 + hf * 32 + skcol),
            AS3(Bs + hf * 4096 + c * 512), 16, 0, 0);
      }
    __syncthreads();                  // staging ready (drains vmcnt)

    if (k0 + 64 < K) {
#pragma unroll
      for (int hf = 0; hf < 2; ++hf)
#pragma unroll
        for (int c = 0; c < 4; ++c)
          pre[hf * 4 + c] = *(const f32x4*)(agp + k0 + 64 + hf * 32 + c * 4);
    }

#pragma unroll
    for (int hf = 0; hf < 2; ++hf) {
      bf16x8 a[4], bfr[4];
#pragma unroll
      for (int i = 0; i < 4; ++i)
        a[i] = *(const bf16x8*)(As + hf * 4096 + (wm * 64 + i * 16 + l16) * 32 + quad * 8);
#pragma unroll
      for (int j = 0; j < 4; ++j)
        bfr[j] = *(const bf16x8*)(Bs + hf * 4096 + (wn * 64 + j * 16 + l16) * 32 + quad * 8);
#pragma unroll
      for (int i = 0; i < 4; ++i)
#pragma unroll
        for (int j = 0; j < 4; ++j)
          acc[i][j] = __builtin_amdgcn_mfma_f32_16x16x32_bf16(a[i], bfr[j], acc[i][j], 0, 0, 0);
    }
  }

#pragma unroll
  for (int j = 0; j < 4; ++j) {
    const int col = col0 + wn * 64 + j * 16 + l16;
    const float bv = bias[col] * bscale;
    if (transv) {
      const int hh = col >> 6, dd = col & 63;
#pragma unroll
      for (int i = 0; i < 4; ++i) {
        const int row = row0 + wm * 64 + i * 16 + quad * 4;
        const int bb2 = row >> 11, tok = row & 2047;
        const int tokp = vperm_tok(tok);
        bf16x4 o;
#pragma unroll
        for (int r2 = 0; r2 < 4; ++r2) o[r2] = (bf16)(acc[i][j][r2] + bv);
        *(bf16x4*)(Cout + (((size_t)bb2 * H_ + hh) * DK + dd) * S_ + tokp) = o;
      }
    } else {
#pragma unroll
      for (int i = 0; i < 4; ++i)
#pragma unroll
        for (int r2 = 0; r2 < 4; ++r2) {
          const int row = row0 + wm * 64 + i * 16 + quad * 4 + r2;
          Cout[(size_t)row * N + col] = (bf16)(acc[i][j][r2] + bv);
        }
    }
  }
}

// ---------------------------------------------------------------------------
// gemm_out: unchanged from R4 (statically-named 4-buffer pipeline).
// ---------------------------------------------------------------------------
__global__ __launch_bounds__(256, 2) void gemm_out(
    const bf16* __restrict__ Ain, const bf16* __restrict__ W,
    const float* __restrict__ bias, float* __restrict__ Cout,
    int M, int N, int K)
{
  const int id = blockIdx.x;
  const int by = id & 63;            // same-by blocks: ids differ by 64
  const int bx = id >> 6;            // 0..7

  __shared__ bf16 As0[2 * 64 * 32], As1[2 * 64 * 32];    // [hf][row][32]
  __shared__ bf16 Bs0[2 * 128 * 32], Bs1[2 * 128 * 32];

  const int tid  = threadIdx.x;
  const int wave = tid >> 6, lane = tid & 63;
  const int quad = lane >> 4, l16 = lane & 15;
  const int wm = wave >> 1, wn = wave & 1;
  const int row0 = by * 64;
  const int col0 = bx * 128;

  const int srow  = lane >> 2;
  const int skcol = (lane & 3) * 8;

  auto stage_A = [&](int k0, bf16* dst) {
#pragma unroll
    for (int hf = 0; hf < 2; ++hf)
      __builtin_amdgcn_global_load_lds(
          AS1C(Ain + (size_t)(row0 + wave * 16 + srow) * K + k0 + hf * 32 + skcol),
          AS3(dst + hf * 2048 + wave * 512), 16, 0, 0);
  };
  auto stage_W = [&](int k0, bf16* dst) {
#pragma unroll
    for (int hf = 0; hf < 2; ++hf)
#pragma unroll
      for (int i = 0; i < 2; ++i) {
        const int c = wave * 2 + i;
        __builtin_amdgcn_global_load_lds(
            AS1C(W + (size_t)(col0 + c * 16 + srow) * K + k0 + hf * 32 + skcol),
            AS3(dst + hf * 4096 + c * 512), 16, 0, 0);
      }
  };

  f32x4 acc[2][4] = {};

  auto mfma_tile = [&](const bf16* Ab, const bf16* Bb) {
#pragma unroll
    for (int hf = 0; hf < 2; ++hf) {
      bf16x8 a[2], bfr[4];
#pragma unroll
      for (int i = 0; i < 2; ++i)
        a[i] = *(const bf16x8*)(Ab + hf * 2048 + (wm * 32 + i * 16 + l16) * 32 + quad * 8);
#pragma unroll
      for (int j = 0; j < 4; ++j)
        bfr[j] = *(const bf16x8*)(Bb + hf * 4096 + (wn * 64 + j * 16 + l16) * 32 + quad * 8);
#pragma unroll
      for (int i = 0; i < 2; ++i)
#pragma unroll
        for (int j = 0; j < 4; ++j)
          acc[i][j] = __builtin_amdgcn_mfma_f32_16x16x32_bf16(a[i], bfr[j], acc[i][j], 0, 0, 0);
    }
  };

  const int NK = K / 64;              // 16, even
  stage_A(0, As0);
  stage_W(0, Bs0);
  __syncthreads();                    // prologue drain

  for (int t2 = 0; t2 < NK / 2; ++t2) {
    const int t = t2 * 2;
    if (t + 1 < NK) { stage_A((t + 1) * 64, As1); stage_W((t + 1) * 64, Bs1); }
    mfma_tile(As0, Bs0);
    __syncthreads();
    if (t + 2 < NK) { stage_A((t + 2) * 64, As0); stage_W((t + 2) * 64, Bs0); }
    mfma_tile(As1, Bs1);
    __syncthreads();
  }

  // Epilogue (fp32 out)
#pragma unroll
  for (int j = 0; j < 4; ++j) {
    const int col = col0 + wn * 64 + j * 16 + l16;
    const float bv = bias[col];
#pragma unroll
    for (int i = 0; i < 2; ++i)
#pragma unroll
      for (int r = 0; r < 4; ++r) {
        const int row = row0 + wm * 32 + i * 16 + quad * 4 + r;
        Cout[(size_t)row * N + col] = acc[i][j][r] + bv;
      }
  }
}

// ---------------------------------------------------------------------------
// Flash attention, R10: depth-2 software pipeline WITHIN each wave (T15
// analog). R6/R8/R9 all plateau at 51-56us regardless of DS count (28 vs 16
// per wave-iter) or conflicts (4.2M vs 0) -> the limiter is the per-wave
// serial chain (K ds_read -> S^T MFMA -> exp2 -> cvt -> PV) at only 2
// waves/SIMD (~60% stall by issue-cost accounting).
// Key observation: K[x] is read ONLY by qkt at iter x-1; V[x] ONLY by pv at
// iter x. So with stageK(t+2) + stageV(t+1) issued at iter t, two K and two
// V static buffers suffice for a depth-2 schedule where S^T(t+1) [MFMA]
// overlaps exp(t) [VALU chain] inside one iteration:
//   iter t: stageK(t+2); stageV(t+1); qkt(t+1) ; exp(t); pv(t); barrier
// sc double-buffered as two NAMED arrays (scA/scB), loop unrolled x2.
// Staging via glds with pre-swizzled global source (0 bank conflicts);
// b128 V reads via vperm'd Vtg. O in-place over Q. Grid 512, XCD swizzle.
// ---------------------------------------------------------------------------
__global__ __launch_bounds__(256, 2) void attn_kernel(
    const bf16* Q, const bf16* __restrict__ Kb,
    const bf16* __restrict__ Vtg, bf16* O)
{
  __shared__ bf16 K0[64 * 64], K1[64 * 64];   // [tok][d], swizzled rows
  __shared__ bf16 V0[64 * 64], V1[64 * 64];   // [d][tok-perm], swizzled

  const int tid  = threadIdx.x;
  const int wave = tid >> 6, lane = tid & 63;
  const int quad = lane >> 4, l16 = lane & 15;
  const int id = blockIdx.x;
  const int hb = id & 31;             // same (b,h) blocks: ids differ by 32
  const int h = hb & 15, b = hb >> 4;
  const int qt = id >> 5;             // 0..15
  const int qA = qt * 128 + wave * 32;
  const size_t base  = (size_t)b * S_ * DM + (size_t)h * DK;   // Q/K/O
  const size_t baseV = ((size_t)b * H_ + h) * DK * S_;         // Vtg

  // Q frags [q=l16][k=quad*8+j], pre-scaled by QSCL via the Wq cast
  bf16x8 qf[2][2];
#pragma unroll
  for (int f = 0; f < 2; ++f)
#pragma unroll
    for (int kt = 0; kt < 2; ++kt)
      qf[f][kt] = *(const bf16x8*)(Q + base + (size_t)(qA + f * 16 + l16) * DM + kt * 32 + quad * 8);

  // glds lane mapping: each glds covers 8 rows x 128B; lane L -> row
  // r0+(L>>3), slot L&7; source slot pre-XORed so LDS[row][c] holds
  // K[row][c ^ ((row&7)<<4)] -- matching the frag-read swizzle.
  const int r8 = lane >> 3;           // == row&7 (r0 is 8-aligned)
  const int so = ((lane & 7) ^ r8) << 3;    // element offset within row
  const bf16* gK = Kb + base;
  const bf16* gV = Vtg + baseV;

  auto stageK = [&](int t, bf16* Kd) {
#pragma unroll
    for (int o8 = 0; o8 < 16; o8 += 8) {
      const int row = wave * 16 + o8 + r8;
      __builtin_amdgcn_global_load_lds(
          AS1C(gK + (size_t)(t * 64 + row) * DM + so),
          AS3(Kd + (wave * 16 + o8) * 64), 16, 0, 0);
    }
  };
  auto stageV = [&](int t, bf16* Vd) {
#pragma unroll
    for (int o8 = 0; o8 < 16; o8 += 8) {
      const int row = wave * 16 + o8 + r8;
      __builtin_amdgcn_global_load_lds(
          AS1C(gV + (size_t)row * S_ + t * 64 + so),
          AS3(Vd + (wave * 16 + o8) * 64), 16, 0, 0);
    }
  };

  f32x4 lacc[2] = {};                  // per-frag per-lane partial sums
  f32x4 accO[2][4] = {};               // O^T[f][d=dt*16+quad*4+r][q=l16]
  const int sw = (l16 & 7) << 4;       // frag-read swizzle (row&7 == l16&7)

  auto qkt = [&](const bf16* Kc_, f32x4 (&sc)[2][4]) {
    const char* Kc = (const char*)Kc_;
#pragma unroll
    for (int ct = 0; ct < 4; ++ct) {
      const char* kp = Kc + (ct * 16 + l16) * 128;
      const bf16x8 kf0 = *(const bf16x8*)(kp + ((quad * 16) ^ sw));
      const bf16x8 kf1 = *(const bf16x8*)(kp + ((64 + quad * 16) ^ sw));
#pragma unroll
      for (int f = 0; f < 2; ++f) {
        f32x4 a = {0.f, 0.f, 0.f, 0.f};
        a = __builtin_amdgcn_mfma_f32_16x16x32_bf16(kf0, qf[f][0], a, 0, 0, 0);
        a = __builtin_amdgcn_mfma_f32_16x16x32_bf16(kf1, qf[f][1], a, 0, 0, 0);
        sc[f][ct] = a;
      }
    }
  };

  auto expv = [&](const f32x4 (&sc)[2][4], bf16x4 (&pk)[2][4]) {
#pragma unroll
    for (int f = 0; f < 2; ++f)
#pragma unroll
      for (int ct = 0; ct < 4; ++ct)
#pragma unroll
        for (int r = 0; r < 4; ++r) {
          const float p = fast_exp2(sc[f][ct][r]);
          lacc[f][r] += p;
          pk[f][ct][r] = (bf16)p;
        }
  };

  auto pv = [&](const bf16* Vc_, const bf16x4 (&pk)[2][4]) {
    const char* Vc = (const char*)Vc_;
#pragma unroll
    for (int dt = 0; dt < 4; ++dt) {
      const char* vp = Vc + (dt * 16 + l16) * 128;
#pragma unroll
      for (int g = 0; g < 2; ++g) {
        const bf16x8 v8 = *(const bf16x8*)(vp + ((g * 64 + quad * 16) ^ sw));
        const bf16x4 vlo = __builtin_shufflevector(v8, v8, 0, 1, 2, 3);
        const bf16x4 vhi = __builtin_shufflevector(v8, v8, 4, 5, 6, 7);
#pragma unroll
        for (int f = 0; f < 2; ++f) {
          accO[f][dt] = mfma_pv(vlo, pk[f][2 * g],     accO[f][dt]);
          accO[f][dt] = mfma_pv(vhi, pk[f][2 * g + 1], accO[f][dt]);
        }
      }
    }
  };

  constexpr int NIT = S_ / 64;        // 32, even
  f32x4 scA[2][4], scB[2][4];

  // prologue: K0<-tile0, K1<-tile1, V0<-tile0; S^T(0); seal K0 reads
  stageK(0, K0);
  stageK(1, K1);
  stageV(0, V0);
  __syncthreads();                    // drains all three glds sets
  qkt(K0, scA);
  __syncthreads();                    // all waves' K0 reads done

  for (int t = 0; t < NIT; t += 2) {
    // even iter t: reads K1(tile t+1), V0(tile t); stages K(t+2)->K0, V(t+1)->V1
    {
      bf16x4 pk[2][4];
      if (t + 2 < NIT) stageK(t + 2, K0);
      stageV(t + 1, V1);              // t+1 <= 31 < NIT always
      qkt(K1, scB);                   // S^T(t+1): overlaps exp(t) below
      expv(scA, pk);                  // exp of tile t (indep of qkt)
      pv(V0, pk);                     // PV of tile t
      __syncthreads();                // drains stages; frees K1-prev, V0
    }
    // odd iter t+1: reads K0(tile t+2), V1(tile t+1); stages K(t+3)->K1, V(t+2)->V0
    {
      bf16x4 pk[2][4];
      if (t + 3 < NIT) stageK(t + 3, K1);
      if (t + 2 < NIT) stageV(t + 2, V0);
      if (t + 2 < NIT) qkt(K0, scA);  // S^T(t+2): overlaps exp(t+1)
      expv(scB, pk);
      pv(V1, pk);
      __syncthreads();
    }
  }

  // ---- epilogue: reduce l per frag, O[q][d] = O^T / l (in-lane) ----
#pragma unroll
  for (int f = 0; f < 2; ++f) {
    float l_s = (lacc[f][0] + lacc[f][1]) + (lacc[f][2] + lacc[f][3]);
    l_s += __shfl_xor(l_s, 16, 64);
    l_s += __shfl_xor(l_s, 32, 64);
    const float inv = 1.0f / l_s;
#pragma unroll
    for (int dt = 0; dt < 4; ++dt) {
      bf16x4 o;
#pragma unroll
      for (int r = 0; r < 4; ++r) o[r] = (bf16)(accO[f][dt][r] * inv);
      *(bf16x4*)(O + base + (size_t)(qA + f * 16 + l16) * DM + dt * 16 + quad * 4) = o;
    }
  }
}

// ---------------------------------------------------------------------------
extern "C" void kernel_launch(void* const* d_in, const int* in_sizes, int n_in,
                              void* d_out, int out_size, void* d_ws, size_t ws_size,
                              hipStream_t stream) {
  (void)in_sizes; (void)n_in; (void)out_size;
  const float* q  = (const float*)d_in[0];
  const float* k  = (const float*)d_in[1];
  const float* v  = (const float*)d_in[2];
  const float* Wq = (const float*)d_in[3];
  const float* bq = (const float*)d_in[4];
  const float* Wk = (const float*)d_in[5];
  const float* bk = (const float*)d_in[6];
  const float* Wv = (const float*)d_in[7];
  const float* bvv= (const float*)d_in[8];
  const float* Wo = (const float*)d_in[9];
  const float* bo = (const float*)d_in[10];
  float* out = (float*)d_out;

  // Workspace plan (MB):
  //  [ 0, 8)  Qb (attn writes O in-place here -> Ab)
  //  [ 8,16)  Kbf
  //  [16,24)  Vtg [b][h][d][tok-perm]
  //  [24,30)  Wc  (Wq,Wk,Wv casts)
  //  [30,32)  WoC (Wo cast)
  //  [32,40)  qc | [40,48) kc | [48,56) vc   } only when ws_size >= 60MB
  char* ws = (char*)d_ws;
  const size_t MB = 1024 * 1024;
  bf16* Qb  = (bf16*)(ws);
  bf16* Kbf = (bf16*)(ws + 8 * MB);
  bf16* Vtg = (bf16*)(ws + 16 * MB);
  bf16* Wc  = (bf16*)(ws + 24 * MB);
  bf16* WoC = (bf16*)(ws + 30 * MB);
  bf16* qc  = (bf16*)(ws + 32 * MB);
  bf16* kc  = (bf16*)(ws + 40 * MB);
  bf16* vc  = (bf16*)(ws + 48 * MB);
  bf16* Ab  = Qb;                     // attn output, in-place over Qb

  const bool big = ws_size >= 60 * MB;
  dim3 bb(256, 1, 1);

  cast_all<<<dim3(big ? 8192 : 2048, 1, 1), bb, 0, stream>>>(
      Wq, Wk, Wv, Wo, q, k, v, Wc, WoC, qc, kc, vc);

  if (big) {
    gemm_qkv_b<<<dim3(768, 1, 1), bb, 0, stream>>>(
        qc, kc, vc, Wc, bq, bk, bvv, Qb, Kbf, Vtg, M_, DM, DM);
  } else {
    gemm_qkv_f<<<dim3(768, 1, 1), bb, 0, stream>>>(
        q, k, v, Wc, bq, bk, bvv, Qb, Kbf, Vtg, M_, DM, DM);
  }

  attn_kernel<<<dim3(512, 1, 1), bb, 0, stream>>>(Qb, Kbf, Vtg, Ab);

  gemm_out<<<dim3(512, 1, 1), bb, 0, stream>>>(Ab, WoC, bo, out, M_, DM, DM);
}

// Round 11
// 208.971 us; speedup vs baseline: 1.0270x; 1.0270x over previous
//
#include <hip/hip_runtime.h>
#include <hip/hip_bf16.h>

typedef __bf16 bf16;
typedef __attribute__((ext_vector_type(4))) __bf16 bf16x4;
typedef __attribute__((ext_vector_type(8))) __bf16 bf16x8;
typedef __attribute__((ext_vector_type(4))) float f32x4;
typedef __attribute__((ext_vector_type(4))) short short4v;

#define AS1C(p) ((const __attribute__((address_space(1))) void*)(p))
#define AS3(p)  ((__attribute__((address_space(3))) void*)(p))

static constexpr int B_ = 2, S_ = 2048, DM = 1024, H_ = 16, DK = 64;
static constexpr int M_ = B_ * S_;   // 4096 tokens
static constexpr int NW = DM * DM;   // 1M weight elems
static constexpr float QSCL = 0.125f * 1.44269504088896340736f;  // (1/sqrt dk)*log2(e)

__device__ __forceinline__ float fast_exp2(float x) {
#if __has_builtin(__builtin_amdgcn_exp2f)
  return __builtin_amdgcn_exp2f(x);
#else
  return exp2f(x);
#endif
}

// 16x16x16 bf16 MFMA (K=16): lets the S^T C-layout (col=l16,row=quad*4+r)
// feed PV's B-operand (col=l16,k=quad*4+j) directly from registers.
__device__ __forceinline__ f32x4 mfma_pv(bf16x4 a, bf16x4 b, f32x4 c) {
#if __has_builtin(__builtin_amdgcn_mfma_f32_16x16x16_bf16)
  return __builtin_amdgcn_mfma_f32_16x16x16_bf16(a, b, c, 0, 0, 0);
#else
  union U { bf16x4 h; short4v s; };
  U ua; ua.h = a;
  U ub; ub.h = b;
  return __builtin_amdgcn_mfma_f32_16x16x16bf16_1k(ua.s, ub.s, c, 0, 0, 0);
#endif
}

// ---------------------------------------------------------------------------
// cast_all: fp32 -> bf16 for weights AND (optionally) activations.
//   id <  512: Wq * QSCL -> Wc[0] | id <1024: Wk | id <1536: Wv | id <2048: Wo
//   id < 4096: q -> qc | id < 6144: k -> kc | id < 8192: v -> vc
// ---------------------------------------------------------------------------
__global__ __launch_bounds__(256) void cast_all(
    const float* Wq, const float* Wk, const float* Wv, const float* Wo,
    const float* q, const float* k, const float* v,
    bf16* Wc, bf16* WoC, bf16* qc, bf16* kc, bf16* vc)
{
  const int id = blockIdx.x;
  const float* in;
  bf16* out;
  float s = 1.0f;
  int base;
  if (id < 2048) {
    const int z = id >> 9;           // 512 blocks per weight
    base = id & 511;
    in  = z == 0 ? Wq : (z == 1 ? Wk : (z == 2 ? Wv : Wo));
    out = z < 3 ? (Wc + (size_t)z * NW) : WoC;
    if (z == 0) s = QSCL;
  } else {
    const int z = (id - 2048) >> 11; // 2048 blocks per activation
    base = (id - 2048) & 2047;
    in  = z == 0 ? q : (z == 1 ? k : v);
    out = z == 0 ? qc : (z == 1 ? kc : vc);
  }
  const size_t i = ((size_t)base * 256 + threadIdx.x) * 8;
  f32x4 a = *(const f32x4*)(in + i);
  f32x4 b2 = *(const f32x4*)(in + i + 4);
  bf16x8 o;
#pragma unroll
  for (int j = 0; j < 4; ++j) { o[j] = (bf16)(a[j] * s); o[4 + j] = (bf16)(b2[j] * s); }
  *(bf16x8*)(out + i) = o;
}

// ---------------------------------------------------------------------------
// gemm_qkv_b (preferred, needs 56MB ws): pure-bf16 m97-structure GEMM.
// Per K-step: barrier / glds A + glds W / barrier(drain) / 32 MFMA.
// Single-buffered 32KB LDS -> 3 blocks/CU; implicit cross-block wave overlap
// covers the drain (m97/m114). Flat grid 768 (3/CU), XCD swizzle.
// transv (z==2) writes Vtg[b][h][d][tok] (plain tok order -- R6 layout).
// ---------------------------------------------------------------------------
__global__ __launch_bounds__(256, 3) void gemm_qkv_b(
    const bf16* __restrict__ qc, const bf16* __restrict__ kc,
    const bf16* __restrict__ vc, const bf16* __restrict__ Wc,
    const float* b0, const float* b1, const float* b2,
    bf16* C0, bf16* C1, bf16* C2, int M, int N, int K)
{
  const int id = blockIdx.x;
  const int z  = id >> 8;            // 0..2
  const int r  = id & 255;
  const int by = r & 31;             // same-by blocks: ids differ by 32
  const int bx = r >> 5;             // 0..7
  const bf16* A = z == 0 ? qc : (z == 1 ? kc : vc);
  const float* bias = z == 0 ? b0 : (z == 1 ? b1 : b2);
  const float bscale = z == 0 ? QSCL : 1.0f;
  const bf16* W = Wc + (size_t)z * NW;
  bf16* Cout = z == 0 ? C0 : (z == 1 ? C1 : C2);
  const bool transv = (z == 2);

  __shared__ bf16 As[2 * 128 * 32];   // [hf][row][32], 16 KB
  __shared__ bf16 Bs[2 * 128 * 32];

  const int tid  = threadIdx.x;
  const int wave = tid >> 6, lane = tid & 63;
  const int quad = lane >> 4, l16 = lane & 15;
  const int wm = wave >> 1, wn = wave & 1;
  const int row0 = by * 128;
  const int col0 = bx * 128;

  const int srow  = lane >> 2;        // glds lane mapping
  const int skcol = (lane & 3) * 8;

  f32x4 acc[4][4] = {};

  for (int k0 = 0; k0 < K; k0 += 64) {
    __syncthreads();                  // prev iter's LDS reads done
#pragma unroll
    for (int hf = 0; hf < 2; ++hf)
#pragma unroll
      for (int c = wave; c < 8; c += 4)
        __builtin_amdgcn_global_load_lds(
            AS1C(A + (size_t)(row0 + c * 16 + srow) * K + k0 + hf * 32 + skcol),
            AS3(As + hf * 4096 + c * 512), 16, 0, 0);
#pragma unroll
    for (int hf = 0; hf < 2; ++hf)
#pragma unroll
      for (int i = 0; i < 2; ++i) {
        const int c = wave * 2 + i;
        __builtin_amdgcn_global_load_lds(
            AS1C(W + (size_t)(col0 + c * 16 + srow) * K + k0 + hf * 32 + skcol),
            AS3(Bs + hf * 4096 + c * 512), 16, 0, 0);
      }
    __syncthreads();                  // staging ready (drains vmcnt)

#pragma unroll
    for (int hf = 0; hf < 2; ++hf) {
      bf16x8 a[4], bfr[4];
#pragma unroll
      for (int i = 0; i < 4; ++i)
        a[i] = *(const bf16x8*)(As + hf * 4096 + (wm * 64 + i * 16 + l16) * 32 + quad * 8);
#pragma unroll
      for (int j = 0; j < 4; ++j)
        bfr[j] = *(const bf16x8*)(Bs + hf * 4096 + (wn * 64 + j * 16 + l16) * 32 + quad * 8);
#pragma unroll
      for (int i = 0; i < 4; ++i)
#pragma unroll
        for (int j = 0; j < 4; ++j)
          acc[i][j] = __builtin_amdgcn_mfma_f32_16x16x32_bf16(a[i], bfr[j], acc[i][j], 0, 0, 0);
    }
  }

  // Epilogue: C/D layout col = lane&15, row = quad*4 + reg
#pragma unroll
  for (int j = 0; j < 4; ++j) {
    const int col = col0 + wn * 64 + j * 16 + l16;
    const float bv = bias[col] * bscale;
    if (transv) {
      const int hh = col >> 6, dd = col & 63;
#pragma unroll
      for (int i = 0; i < 4; ++i) {
        const int row = row0 + wm * 64 + i * 16 + quad * 4;
        const int bb2 = row >> 11, tok = row & 2047;
        bf16x4 o;
#pragma unroll
        for (int r2 = 0; r2 < 4; ++r2) o[r2] = (bf16)(acc[i][j][r2] + bv);
        *(bf16x4*)(Cout + (((size_t)bb2 * H_ + hh) * DK + dd) * S_ + tok) = o;
      }
    } else {
#pragma unroll
      for (int i = 0; i < 4; ++i)
#pragma unroll
        for (int r2 = 0; r2 < 4; ++r2) {
          const int row = row0 + wm * 64 + i * 16 + quad * 4 + r2;
          Cout[(size_t)row * N + col] = (bf16)(acc[i][j][r2] + bv);
        }
    }
  }
}

// ---------------------------------------------------------------------------
// gemm_qkv_f (fallback, 32MB ws): fp32-A path, exact R2/R4 schedule.
// ---------------------------------------------------------------------------
__global__ __launch_bounds__(256) void gemm_qkv_f(
    const float* A0, const float* A1, const float* A2,
    const bf16* __restrict__ Wc,
    const float* b0, const float* b1, const float* b2,
    bf16* C0, bf16* C1, bf16* C2, int M, int N, int K)
{
  const int id = blockIdx.x;
  const int z  = id >> 8;            // 0..2
  const int r  = id & 255;
  const int by = r & 31;             // same-by blocks: ids differ by 32
  const int bx = r >> 5;             // 0..7
  const float* A = z == 0 ? A0 : (z == 1 ? A1 : A2);
  const float* bias = z == 0 ? b0 : (z == 1 ? b1 : b2);
  const float bscale = z == 0 ? QSCL : 1.0f;
  const bf16* W = Wc + (size_t)z * NW;
  bf16* Cout = z == 0 ? C0 : (z == 1 ? C1 : C2);
  const bool transv = (z == 2);

  __shared__ bf16 As[2 * 128 * 32];   // [hf][row][32]
  __shared__ bf16 Bs[2 * 128 * 32];

  const int tid  = threadIdx.x;
  const int wave = tid >> 6, lane = tid & 63;
  const int quad = lane >> 4, l16 = lane & 15;
  const int wm = wave >> 1, wn = wave & 1;
  const int row0 = by * 128;
  const int col0 = bx * 128;

  const int srow  = lane >> 2;        // glds lane mapping
  const int skcol = (lane & 3) * 8;

  const int arow  = (tid >> 1) & 127;
  const int ak16  = (tid & 1) * 16;
  const float* agp = A + (size_t)(row0 + arow) * K + ak16;
  f32x4 pre[8];
#pragma unroll
  for (int hf = 0; hf < 2; ++hf)
#pragma unroll
    for (int c = 0; c < 4; ++c)
      pre[hf * 4 + c] = *(const f32x4*)(agp + hf * 32 + c * 4);

  f32x4 acc[4][4] = {};

  for (int k0 = 0; k0 < K; k0 += 64) {
    __syncthreads();                  // prev iter's LDS reads done
#pragma unroll
    for (int hf = 0; hf < 2; ++hf) {
      bf16x8 w0, w1;
#pragma unroll
      for (int j = 0; j < 4; ++j) {
        w0[j]     = (bf16)pre[hf * 4 + 0][j];
        w0[4 + j] = (bf16)pre[hf * 4 + 1][j];
        w1[j]     = (bf16)pre[hf * 4 + 2][j];
        w1[4 + j] = (bf16)pre[hf * 4 + 3][j];
      }
      bf16* dst = As + hf * 4096 + arow * 32 + ak16;
      *(bf16x8*)dst = w0;
      *(bf16x8*)(dst + 8) = w1;
    }
#pragma unroll
    for (int hf = 0; hf < 2; ++hf)
#pragma unroll
      for (int i = 0; i < 2; ++i) {
        const int c = wave * 2 + i;
        __builtin_amdgcn_global_load_lds(
            AS1C(W + (size_t)(col0 + c * 16 + srow) * K + k0 + hf * 32 + skcol),
            AS3(Bs + hf * 4096 + c * 512), 16, 0, 0);
      }
    __syncthreads();                  // staging ready (drains vmcnt)

    if (k0 + 64 < K) {
#pragma unroll
      for (int hf = 0; hf < 2; ++hf)
#pragma unroll
        for (int c = 0; c < 4; ++c)
          pre[hf * 4 + c] = *(const f32x4*)(agp + k0 + 64 + hf * 32 + c * 4);
    }

#pragma unroll
    for (int hf = 0; hf < 2; ++hf) {
      bf16x8 a[4], bfr[4];
#pragma unroll
      for (int i = 0; i < 4; ++i)
        a[i] = *(const bf16x8*)(As + hf * 4096 + (wm * 64 + i * 16 + l16) * 32 + quad * 8);
#pragma unroll
      for (int j = 0; j < 4; ++j)
        bfr[j] = *(const bf16x8*)(Bs + hf * 4096 + (wn * 64 + j * 16 + l16) * 32 + quad * 8);
#pragma unroll
      for (int i = 0; i < 4; ++i)
#pragma unroll
        for (int j = 0; j < 4; ++j)
          acc[i][j] = __builtin_amdgcn_mfma_f32_16x16x32_bf16(a[i], bfr[j], acc[i][j], 0, 0, 0);
    }
  }

#pragma unroll
  for (int j = 0; j < 4; ++j) {
    const int col = col0 + wn * 64 + j * 16 + l16;
    const float bv = bias[col] * bscale;
    if (transv) {
      const int hh = col >> 6, dd = col & 63;
#pragma unroll
      for (int i = 0; i < 4; ++i) {
        const int row = row0 + wm * 64 + i * 16 + quad * 4;
        const int bb2 = row >> 11, tok = row & 2047;
        bf16x4 o;
#pragma unroll
        for (int r2 = 0; r2 < 4; ++r2) o[r2] = (bf16)(acc[i][j][r2] + bv);
        *(bf16x4*)(Cout + (((size_t)bb2 * H_ + hh) * DK + dd) * S_ + tok) = o;
      }
    } else {
#pragma unroll
      for (int i = 0; i < 4; ++i)
#pragma unroll
        for (int r2 = 0; r2 < 4; ++r2) {
          const int row = row0 + wm * 64 + i * 16 + quad * 4 + r2;
          Cout[(size_t)row * N + col] = (bf16)(acc[i][j][r2] + bv);
        }
    }
  }
}

// ---------------------------------------------------------------------------
// gemm_out R11: m97-structure port. 64x64 tile, SINGLE-buffered 16KB LDS,
// 2-barrier K-step (stage glds / barrier-drain / MFMA), grid 1024 =
// 4 blocks/CU (vs old 64x128 4-buffer pipeline at 2 blocks/CU, which was
// never counter-validated and has half qkv_b's MFMA:glds ratio).
// Rationale: m97/m114 -- implicit cross-block wave overlap covers the
// drain; 4 blocks/CU gives MORE overlap than qkv_b's 3. W/A re-reads grow
// (128MB each from L2) but both are L2-resident. XCD swizzle: same-by ids
// differ by 64 (== 0 mod 8) -> same XCD for the A row-strip.
// ---------------------------------------------------------------------------
__global__ __launch_bounds__(256, 4) void gemm_out(
    const bf16* __restrict__ Ain, const bf16* __restrict__ W,
    const float* __restrict__ bias, float* __restrict__ Cout,
    int M, int N, int K)
{
  const int id = blockIdx.x;
  const int by = id & 63;            // 0..63: same-by blocks ids differ by 64
  const int bx = id >> 6;            // 0..15

  __shared__ bf16 As[2 * 64 * 32];   // [hf][row][32], 8 KB
  __shared__ bf16 Bs[2 * 64 * 32];   // 8 KB

  const int tid  = threadIdx.x;
  const int wave = tid >> 6, lane = tid & 63;
  const int quad = lane >> 4, l16 = lane & 15;
  const int wm = wave >> 1, wn = wave & 1;
  const int row0 = by * 64;
  const int col0 = bx * 64;

  const int srow  = lane >> 2;
  const int skcol = (lane & 3) * 8;

  f32x4 acc[2][2] = {};

  for (int k0 = 0; k0 < K; k0 += 64) {
    __syncthreads();                  // prev iter's LDS reads done
#pragma unroll
    for (int hf = 0; hf < 2; ++hf) {
      __builtin_amdgcn_global_load_lds(
          AS1C(Ain + (size_t)(row0 + wave * 16 + srow) * K + k0 + hf * 32 + skcol),
          AS3(As + hf * 2048 + wave * 512), 16, 0, 0);
      __builtin_amdgcn_global_load_lds(
          AS1C(W + (size_t)(col0 + wave * 16 + srow) * K + k0 + hf * 32 + skcol),
          AS3(Bs + hf * 2048 + wave * 512), 16, 0, 0);
    }
    __syncthreads();                  // staging ready (drains vmcnt)

#pragma unroll
    for (int hf = 0; hf < 2; ++hf) {
      bf16x8 a[2], bfr[2];
#pragma unroll
      for (int i = 0; i < 2; ++i)
        a[i] = *(const bf16x8*)(As + hf * 2048 + (wm * 32 + i * 16 + l16) * 32 + quad * 8);
#pragma unroll
      for (int j = 0; j < 2; ++j)
        bfr[j] = *(const bf16x8*)(Bs + hf * 2048 + (wn * 32 + j * 16 + l16) * 32 + quad * 8);
#pragma unroll
      for (int i = 0; i < 2; ++i)
#pragma unroll
        for (int j = 0; j < 2; ++j)
          acc[i][j] = __builtin_amdgcn_mfma_f32_16x16x32_bf16(a[i], bfr[j], acc[i][j], 0, 0, 0);
    }
  }

  // Epilogue (fp32 out): col = lane&15, row = quad*4 + reg
#pragma unroll
  for (int j = 0; j < 2; ++j) {
    const int col = col0 + wn * 32 + j * 16 + l16;
    const float bv = bias[col];
#pragma unroll
    for (int i = 0; i < 2; ++i)
#pragma unroll
      for (int r = 0; r < 4; ++r) {
        const int row = row0 + wm * 32 + i * 16 + quad * 4 + r;
        Cout[(size_t)row * N + col] = acc[i][j][r] + bv;
      }
  }
}

// ---------------------------------------------------------------------------
// Flash attention — EXACT R6 form (best measured: 51.6us). S^T/O^T, no
// online max; log2-domain scores (Wq pre-scaled). Block = 128 q (4 waves x
// 32 q: two 16-q frags/wave). KV tile 64, DOUBLE-buffered K/V in LDS (one
// barrier per iter), REGISTER prefetch (global->reg a full iteration early;
// ds_write at point of use -- beats all glds-staged variants R8/R9/R10).
// P^T stays in registers (16x16x16 PV MFMA, B-frag == S^T C-frag).
// Kt/Vt: stride 64 + 16B-slot XOR swizzle (byte ^= (row&7)<<4).
// V pre-transposed globally (Vtg[b][h][d][tok], plain tok). O written
// IN-PLACE over Q. Flat grid (512) with XCD swizzle.
// ---------------------------------------------------------------------------
__global__ __launch_bounds__(256, 2) void attn_kernel(
    const bf16* Q, const bf16* __restrict__ Kb,
    const bf16* __restrict__ Vtg, bf16* O)
{
  __shared__ bf16 Kt[2 * 64 * 64];    // [buf][tok][d], XOR-swizzled rows
  __shared__ bf16 Vt[2 * 64 * 64];    // [buf][d][tok], XOR-swizzled rows

  const int tid  = threadIdx.x;
  const int wave = tid >> 6, lane = tid & 63;
  const int quad = lane >> 4, l16 = lane & 15;
  const int id = blockIdx.x;
  const int hb = id & 31;             // same (b,h) blocks: ids differ by 32
  const int h = hb & 15, b = hb >> 4;
  const int qt = id >> 5;             // 0..15
  const int qA = qt * 128 + wave * 32;
  const size_t base  = (size_t)b * S_ * DM + (size_t)h * DK;   // Q/K/O
  const size_t baseV = ((size_t)b * H_ + h) * DK * S_;         // Vtg

  // Q frags [q=l16][k=quad*8+j], pre-scaled by QSCL via the Wq cast
  bf16x8 qf[2][2];
#pragma unroll
  for (int f = 0; f < 2; ++f)
#pragma unroll
    for (int kt = 0; kt < 2; ++kt)
      qf[f][kt] = *(const bf16x8*)(Q + base + (size_t)(qA + f * 16 + l16) * DM + kt * 32 + quad * 8);

  // staging: waves 0-1 -> K rows (tok), waves 2-3 -> V^T rows (d)
  const bool kside = (wave < 2);
  const int srow  = kside ? (tid >> 1) : ((tid - 128) >> 1);   // 0..63
  const int shalf = tid & 1;
  const bf16* gp = kside
      ? (Kb + base + (size_t)srow * DM + shalf * 32)
      : (Vtg + baseV + (size_t)srow * S_ + shalf * 32);
  const size_t gstep = kside ? (size_t)64 * DM : 64;
  char* sb = (char*)(kside ? (void*)Kt : (void*)Vt) + srow * 128;
  const int sw_s = (srow & 7) << 4;

  // prologue: tile 0 -> buf0, prefetch tile 1 into regs
  bf16x8 st[4];
#pragma unroll
  for (int c = 0; c < 4; ++c) st[c] = *(const bf16x8*)(gp + c * 8);
  gp += gstep;
#pragma unroll
  for (int c = 0; c < 4; ++c)
    *(bf16x8*)(sb + ((shalf * 64 + c * 16) ^ sw_s)) = st[c];
#pragma unroll
  for (int c = 0; c < 4; ++c) st[c] = *(const bf16x8*)(gp + c * 8);
  gp += gstep;

  f32x4 lacc[2] = {};                  // per-frag per-lane partial sums
  f32x4 accO[2][4] = {};               // O^T[f][d=dt*16+quad*4+r][q=l16]
  const int sw = (l16 & 7) << 4;       // frag-read swizzle (row&7 == l16&7)

  __syncthreads();                     // buf0 ready

  constexpr int NIT = S_ / 64;
  for (int it = 0; it < NIT; ++it) {
    const int cur = it & 1, nxt = cur ^ 1;
    const char* Kc = (const char*)Kt + cur * 8192;
    const char* Vc = (const char*)Vt + cur * 8192;

    // ---- S^T: 4 tok-tiles x 2 q-frags; K frags shared across frags ----
    f32x4 sc[2][4];
#pragma unroll
    for (int ct = 0; ct < 4; ++ct) {
      const char* kp = Kc + (ct * 16 + l16) * 128;
      const bf16x8 kf0 = *(const bf16x8*)(kp + ((quad * 16) ^ sw));
      const bf16x8 kf1 = *(const bf16x8*)(kp + ((64 + quad * 16) ^ sw));
#pragma unroll
      for (int f = 0; f < 2; ++f) {
        f32x4 a = {0.f, 0.f, 0.f, 0.f};
        a = __builtin_amdgcn_mfma_f32_16x16x32_bf16(kf0, qf[f][0], a, 0, 0, 0);
        a = __builtin_amdgcn_mfma_f32_16x16x32_bf16(kf1, qf[f][1], a, 0, 0, 0);
        sc[f][ct] = a;
      }
    }

    // ---- stage tile it+1 into buf[nxt] (safe: buf[nxt] reads ended at the
    //      previous barrier), then prefetch tile it+2 into regs ----
    if (it + 1 < NIT) {
#pragma unroll
      for (int c = 0; c < 4; ++c)
        *(bf16x8*)(sb + nxt * 8192 + ((shalf * 64 + c * 16) ^ sw_s)) = st[c];
      if (it + 2 < NIT) {
#pragma unroll
        for (int c = 0; c < 4; ++c) st[c] = *(const bf16x8*)(gp + c * 8);
        gp += gstep;
      }
    }

    // ---- p = exp2(sc); P^T stays in registers as 16x16x16 B-frags ----
    bf16x4 pk[2][4];
#pragma unroll
    for (int f = 0; f < 2; ++f)
#pragma unroll
      for (int ct = 0; ct < 4; ++ct)
#pragma unroll
        for (int r = 0; r < 4; ++r) {
          const float p = fast_exp2(sc[f][ct][r]);
          lacc[f][r] += p;
          pk[f][ct][r] = (bf16)p;
        }

    // ---- O^T += V^T P  (K=16 per ct tile); V frags shared across frags ----
#pragma unroll
    for (int dt = 0; dt < 4; ++dt) {
      const char* vp = Vc + (dt * 16 + l16) * 128;
#pragma unroll
      for (int ct = 0; ct < 4; ++ct) {
        const bf16x4 vf = *(const bf16x4*)(vp + ((ct * 32 + quad * 8) ^ sw));
#pragma unroll
        for (int f = 0; f < 2; ++f)
          accO[f][dt] = mfma_pv(vf, pk[f][ct], accO[f][dt]);
      }
    }

    __syncthreads();                   // publishes buf[nxt]; buf[cur] reads done
  }

  // ---- epilogue: reduce l per frag, O[q][d] = O^T / l (in-lane) ----
#pragma unroll
  for (int f = 0; f < 2; ++f) {
    float l_s = (lacc[f][0] + lacc[f][1]) + (lacc[f][2] + lacc[f][3]);
    l_s += __shfl_xor(l_s, 16, 64);
    l_s += __shfl_xor(l_s, 32, 64);
    const float inv = 1.0f / l_s;
#pragma unroll
    for (int dt = 0; dt < 4; ++dt) {
      bf16x4 o;
#pragma unroll
      for (int r = 0; r < 4; ++r) o[r] = (bf16)(accO[f][dt][r] * inv);
      *(bf16x4*)(O + base + (size_t)(qA + f * 16 + l16) * DM + dt * 16 + quad * 4) = o;
    }
  }
}

// ---------------------------------------------------------------------------
extern "C" void kernel_launch(void* const* d_in, const int* in_sizes, int n_in,
                              void* d_out, int out_size, void* d_ws, size_t ws_size,
                              hipStream_t stream) {
  (void)in_sizes; (void)n_in; (void)out_size;
  const float* q  = (const float*)d_in[0];
  const float* k  = (const float*)d_in[1];
  const float* v  = (const float*)d_in[2];
  const float* Wq = (const float*)d_in[3];
  const float* bq = (const float*)d_in[4];
  const float* Wk = (const float*)d_in[5];
  const float* bk = (const float*)d_in[6];
  const float* Wv = (const float*)d_in[7];
  const float* bvv= (const float*)d_in[8];
  const float* Wo = (const float*)d_in[9];
  const float* bo = (const float*)d_in[10];
  float* out = (float*)d_out;

  // Workspace plan (MB):
  //  [ 0, 8)  Qb (attn writes O in-place here -> Ab)
  //  [ 8,16)  Kbf
  //  [16,24)  Vtg [b][h][d][tok]
  //  [24,30)  Wc  (Wq,Wk,Wv casts)
  //  [30,32)  WoC (Wo cast)
  //  [32,40)  qc | [40,48) kc | [48,56) vc   } only when ws_size >= 60MB
  char* ws = (char*)d_ws;
  const size_t MB = 1024 * 1024;
  bf16* Qb  = (bf16*)(ws);
  bf16* Kbf = (bf16*)(ws + 8 * MB);
  bf16* Vtg = (bf16*)(ws + 16 * MB);
  bf16* Wc  = (bf16*)(ws + 24 * MB);
  bf16* WoC = (bf16*)(ws + 30 * MB);
  bf16* qc  = (bf16*)(ws + 32 * MB);
  bf16* kc  = (bf16*)(ws + 40 * MB);
  bf16* vc  = (bf16*)(ws + 48 * MB);
  bf16* Ab  = Qb;                     // attn output, in-place over Qb

  const bool big = ws_size >= 60 * MB;
  dim3 bb(256, 1, 1);

  cast_all<<<dim3(big ? 8192 : 2048, 1, 1), bb, 0, stream>>>(
      Wq, Wk, Wv, Wo, q, k, v, Wc, WoC, qc, kc, vc);

  if (big) {
    gemm_qkv_b<<<dim3(768, 1, 1), bb, 0, stream>>>(
        qc, kc, vc, Wc, bq, bk, bvv, Qb, Kbf, Vtg, M_, DM, DM);
  } else {
    gemm_qkv_f<<<dim3(768, 1, 1), bb, 0, stream>>>(
        q, k, v, Wc, bq, bk, bvv, Qb, Kbf, Vtg, M_, DM, DM);
  }

  attn_kernel<<<dim3(512, 1, 1), bb, 0, stream>>>(Qb, Kbf, Vtg, Ab);

  gemm_out<<<dim3(1024, 1, 1), bb, 0, stream>>>(Ab, WoC, bo, out, M_, DM, DM);
}